// Round 9
// baseline (739.452 us; speedup 1.0000x reference)
//
#include <hip/hip_runtime.h>
#include <cstdint>
#include <cstddef>

// ====================================================================
// Attention block: out = softmax(mask? NEG : (QK^T*scale + bias)) V @ Wout^T
// B=8 L=1024 E=1024 H=16 A=64.
// float inputs -> const float*, bool mask -> const int*, output -> float*.
// This round: k_attn = measured-best R4 structure (unchanged). Two
// DIAGNOSTIC kernels appended (run last, write only to scratch):
//   k_diag_pat : bias+mask of heads 0-63 read with the exact attn
//                fragment pattern (16 rows x 64B per wave-instruction).
//   k_diag_flat: bias+mask of heads 64-127 read fully contiguously
//                (1KB per wave-instruction).
// Their rocprof rows give a clean A/B of "pattern vs flat" streaming BW
// to identify why every attn variant pins at ~1.9 TB/s.
// ====================================================================

typedef __bf16 bf16;
typedef __attribute__((ext_vector_type(8))) __bf16 bf16x8;
typedef __attribute__((ext_vector_type(2))) __bf16 bf16x2;
typedef __attribute__((ext_vector_type(4))) float f32x4;
typedef __attribute__((ext_vector_type(4))) int i32x4;

#define MFMA_BF16(a, b, c) __builtin_amdgcn_mfma_f32_16x16x32_bf16(a, b, c, 0, 0, 0)

static constexpr float SCALE_ = 0.125f;                     // 64^-0.5
static constexpr float NEGF  = -3.4028234663852886e38f;     // finfo(f32).min

__device__ __forceinline__ void gload_lds16(const bf16* g, bf16* l) {
  __builtin_amdgcn_global_load_lds((const __attribute__((address_space(1))) void*)g,
                                   (__attribute__((address_space(3))) void*)l,
                                   16, 0, 0);
}

__device__ __forceinline__ bf16x8 cvt8(const float* p) {
  f32x4 a = *(const f32x4*)p;
  f32x4 b = *(const f32x4*)(p + 4);
  bf16x8 r = {(bf16)a[0], (bf16)a[1], (bf16)a[2], (bf16)a[3],
              (bf16)b[0], (bf16)b[1], (bf16)b[2], (bf16)b[3]};
  return r;
}

// --------------------------------------------------------------------
// Kernel 1: QKV projection.  C[8192,3072] = X[8192,1024] @ W[3072,1024]^T
// --------------------------------------------------------------------
__global__ __launch_bounds__(256) void k_qkv(const float* __restrict__ X,
                                             const float* __restrict__ W,
                                             bf16* __restrict__ Q,
                                             bf16* __restrict__ Kc,
                                             bf16* __restrict__ Vt) {
  constexpr int K = 1024;
  __shared__ __align__(16) bf16 As[128 * 64];
  __shared__ __align__(16) bf16 Bs[128 * 64];
  const int t = threadIdx.x;
  const int lane = t & 63, w = t >> 6;
  const int wr = w >> 1, wc = w & 1;
  const int li = lane & 15, g = lane >> 4;
  const int m0 = (blockIdx.x & 63) * 128;   // 64 m-tiles
  const int n0 = (blockIdx.x >> 6) * 128;   // 24 n-tiles

  f32x4 acc[4][4] = {};

  for (int kt = 0; kt < K; kt += 64) {
#pragma unroll
    for (int it = 0; it < 4; ++it) {
      int c = it * 256 + t;               // 0..1023, 8 bf16 elems each
      int row = c >> 3, col = (c & 7) << 3;
      *(bf16x8*)(As + c * 8) = cvt8(X + (size_t)(m0 + row) * K + kt + col);
      *(bf16x8*)(Bs + c * 8) = cvt8(W + (size_t)(n0 + row) * K + kt + col);
    }
    __syncthreads();
#pragma unroll
    for (int kk = 0; kk < 2; ++kk) {
      bf16x8 af[4], bfr[4];
#pragma unroll
      for (int i = 0; i < 4; ++i)
        af[i] = *(const bf16x8*)(As + (wr * 64 + i * 16 + li) * 64 + kk * 32 + g * 8);
#pragma unroll
      for (int j = 0; j < 4; ++j)
        bfr[j] = *(const bf16x8*)(Bs + (wc * 64 + j * 16 + li) * 64 + kk * 32 + g * 8);
#pragma unroll
      for (int i = 0; i < 4; ++i)
#pragma unroll
        for (int j = 0; j < 4; ++j)
          acc[i][j] = MFMA_BF16(af[i], bfr[j], acc[i][j]);
    }
    __syncthreads();
  }

#pragma unroll
  for (int i = 0; i < 4; ++i) {
#pragma unroll
    for (int j = 0; j < 4; ++j) {
      int col = n0 + wc * 64 + j * 16 + li;
      int h = col / 192, r = col % 192;
#pragma unroll
      for (int rg = 0; rg < 4; ++rg) {
        int row = m0 + wr * 64 + i * 16 + g * 4 + rg;
        int b = row >> 10, l = row & 1023;
        bf16 v = (bf16)acc[i][j][rg];
        if (r < 64)
          Q[((size_t)((b * 16 + h) * 1024 + l)) * 64 + r] = v;
        else if (r < 128)
          Kc[((size_t)((b * 16 + h) * 1024 + l)) * 64 + (r - 64)] = v;
        else
          Vt[((size_t)((b * 16 + h) * 64 + (r - 128))) * 1024 + l] = v;
      }
    }
  }
}

// --------------------------------------------------------------------
// Kernel 2: flash attention (R4 measured-best structure, unchanged).
// --------------------------------------------------------------------
__global__ __launch_bounds__(256) void k_attn(const bf16* __restrict__ Q,
                                              const bf16* __restrict__ Kc,
                                              const bf16* __restrict__ Vt,
                                              const float* __restrict__ bias,
                                              const int* __restrict__ mask,
                                              bf16* __restrict__ Vals) {
  __shared__ __align__(16) bf16 Plds[4][2][16][72];  // per-wave, pad-72 rows
  const int t = threadIdx.x, lane = t & 63, w = t >> 6;
  const int li = lane & 15, g = lane >> 4;
  const int lid = blockIdx.x;
  const int bh = lid & 127;            // b*16+h; lid%8 == bh%8 -> same XCD
  const int qt = lid >> 7;
  const int b = bh >> 4, h = bh & 15;
  const int q0 = qt * 64 + w * 16;     // wave's 16 q rows

  const bf16* Qbase = Q + ((size_t)bh << 10) * 64;
  const bf16* Kbase = Kc + ((size_t)bh << 10) * 64;
  const bf16* Vbase = Vt + ((size_t)bh << 6) * 1024;
  const float* brow = bias + ((size_t)bh << 20) + (size_t)(q0 + li) * 1024 + g * 4;
  const int*   mrow = mask + ((size_t)bh << 20) + (size_t)(q0 + li) * 1024 + g * 4;

  bf16x8 qf[2];
#pragma unroll
  for (int c = 0; c < 2; ++c)
    qf[c] = *(const bf16x8*)(Qbase + (size_t)(q0 + li) * 64 + c * 32 + g * 8);

  f32x4 oacc[4] = {};
  float mrun = NEGF;
  float lrun = 0.f;

  // ---- prologue: issue tile-0 bias/mask loads ----
  f32x4 b4[4];
  i32x4 m4[4];
#pragma unroll
  for (int kkf = 0; kkf < 4; ++kkf) {
    b4[kkf] = *(const f32x4*)(brow + kkf * 16);
    m4[kkf] = *(const i32x4*)(mrow + kkf * 16);
  }

  for (int kt6 = 0; kt6 < 16; ++kt6) {
    const int kkt = kt6 * 64;
    const int par = kt6 & 1;

    // ---- consume prefetched bias/mask: fold mask into bias ----
    f32x4 c4[4];
#pragma unroll
    for (int kkf = 0; kkf < 4; ++kkf)
#pragma unroll
      for (int rg = 0; rg < 4; ++rg)
        c4[kkf][rg] = m4[kkf][rg] ? NEGF : b4[kkf][rg];

    // ---- issue next tile's bias/mask loads ----
    if (kt6 < 15) {
#pragma unroll
      for (int kkf = 0; kkf < 4; ++kkf) {
        b4[kkf] = *(const f32x4*)(brow + kkt + 64 + kkf * 16);
        m4[kkf] = *(const i32x4*)(mrow + kkt + 64 + kkf * 16);
      }
    }

    // ---- S^T = K Q^T ----
    f32x4 s[4];
#pragma unroll
    for (int kkf = 0; kkf < 4; ++kkf) {
      f32x4 ss = {0.f, 0.f, 0.f, 0.f};
#pragma unroll
      for (int c = 0; c < 2; ++c) {
        bf16x8 kf = *(const bf16x8*)(Kbase + (size_t)(kkt + kkf * 16 + li) * 64 + c * 32 + g * 8);
        ss = MFMA_BF16(kf, qf[c], ss);
      }
      s[kkf] = ss;
    }

    // ---- scale + masked-bias, tile max ----
    float tmax = NEGF;
#pragma unroll
    for (int kkf = 0; kkf < 4; ++kkf) {
#pragma unroll
      for (int rg = 0; rg < 4; ++rg) {
        float sv = __builtin_fmaf(s[kkf][rg], SCALE_, c4[kkf][rg]);
        s[kkf][rg] = sv;
        tmax = fmaxf(tmax, sv);
      }
    }
    tmax = fmaxf(tmax, __shfl_xor(tmax, 16));
    tmax = fmaxf(tmax, __shfl_xor(tmax, 32));

    float mnew = fmaxf(mrun, tmax);
    float corr = __expf(mrun - mnew);   // NEG-NEG=0 -> 1; NEG-real -> 0
    float psum = 0.f;

    // ---- P = exp(s - m): pack pairs, b32 LDS writes ----
#pragma unroll
    for (int kkf = 0; kkf < 4; ++kkf) {
      float p0 = __expf(s[kkf][0] - mnew);
      float p1 = __expf(s[kkf][1] - mnew);
      float p2 = __expf(s[kkf][2] - mnew);
      float p3 = __expf(s[kkf][3] - mnew);
      psum += (p0 + p1) + (p2 + p3);
      bf16x2 pa = {(bf16)p0, (bf16)p1};
      bf16x2 pb = {(bf16)p2, (bf16)p3};
      *(bf16x2*)(&Plds[w][par][li][kkf * 16 + g * 4])     = pa;
      *(bf16x2*)(&Plds[w][par][li][kkf * 16 + g * 4 + 2]) = pb;
    }
    psum += __shfl_xor(psum, 16);
    psum += __shfl_xor(psum, 32);
    lrun = lrun * corr + psum;
    mrun = mnew;

    // ---- rescale O ----
    float cq[4];
#pragma unroll
    for (int rg = 0; rg < 4; ++rg) cq[rg] = __shfl(corr, g * 4 + rg);
#pragma unroll
    for (int af = 0; af < 4; ++af)
#pragma unroll
      for (int rg = 0; rg < 4; ++rg) oacc[af][rg] *= cq[rg];

    // ---- O += P V ----
#pragma unroll
    for (int c = 0; c < 2; ++c) {
      bf16x8 pf = *(const bf16x8*)(&Plds[w][par][li][c * 32 + g * 8]);
#pragma unroll
      for (int af = 0; af < 4; ++af) {
        bf16x8 vf = *(const bf16x8*)(Vbase + (size_t)(af * 16 + li) * 1024 + kkt + c * 32 + g * 8);
        oacc[af] = MFMA_BF16(pf, vf, oacc[af]);
      }
    }
  }

  float linv[4];
#pragma unroll
  for (int rg = 0; rg < 4; ++rg) linv[rg] = 1.0f / __shfl(lrun, g * 4 + rg);
#pragma unroll
  for (int af = 0; af < 4; ++af) {
#pragma unroll
    for (int rg = 0; rg < 4; ++rg) {
      int q = q0 + g * 4 + rg;
      int col = h * 64 + af * 16 + li;
      Vals[(((size_t)(b * 1024 + q)) << 10) + col] = (bf16)(oacc[af][rg] * linv[rg]);
    }
  }
}

// --------------------------------------------------------------------
// Diagnostic A: attn-pattern reader. Heads 0..63 (1024 blocks).
// Same per-lane addresses as k_attn's bias/mask fragment loads.
// --------------------------------------------------------------------
__global__ __launch_bounds__(256) void k_diag_pat(const float* __restrict__ bias,
                                                  const int* __restrict__ mask,
                                                  float* __restrict__ sink) {
  const int t = threadIdx.x, lane = t & 63, w = t >> 6;
  const int li = lane & 15, g = lane >> 4;
  const int lid = blockIdx.x;
  const int bh = lid & 63;             // heads 0..63
  const int qt = lid >> 6;
  const int q0 = qt * 64 + w * 16;

  const float* brow = bias + ((size_t)bh << 20) + (size_t)(q0 + li) * 1024 + g * 4;
  const int*   mrow = mask + ((size_t)bh << 20) + (size_t)(q0 + li) * 1024 + g * 4;

  float fs = 0.f;
  int   is = 0;
  for (int kkt = 0; kkt < 1024; kkt += 64) {
#pragma unroll
    for (int kkf = 0; kkf < 4; ++kkf) {
      f32x4 b4 = *(const f32x4*)(brow + kkt + kkf * 16);
      i32x4 m4 = *(const i32x4*)(mrow + kkt + kkf * 16);
      fs += (b4[0] + b4[1]) + (b4[2] + b4[3]);
      is += (m4[0] + m4[1]) + (m4[2] + m4[3]);
    }
  }
  sink[(size_t)lid * 256 + t] = fs + (float)is;
}

// --------------------------------------------------------------------
// Diagnostic B: flat contiguous reader. Heads 64..127 (1024 blocks).
// Each wave streams a 64 KB f32 (+64 KB i32) region; every wave
// instruction covers a contiguous 1 KB span.
// --------------------------------------------------------------------
__global__ __launch_bounds__(256) void k_diag_flat(const float* __restrict__ bias,
                                                   const int* __restrict__ mask,
                                                   float* __restrict__ sink) {
  const int t = threadIdx.x, lane = t & 63, w = t >> 6;
  const int lid = blockIdx.x;
  const int bh = 64 + (lid & 63);      // heads 64..127
  const int qt = lid >> 6;

  const float* bp = bias + ((size_t)bh << 20) + (size_t)qt * 65536 + (size_t)w * 16384;
  const int*   mp = mask + ((size_t)bh << 20) + (size_t)qt * 65536 + (size_t)w * 16384;

  float fs = 0.f;
  int   is = 0;
  for (int it = 0; it < 16; ++it) {
#pragma unroll
    for (int v = 0; v < 4; ++v) {
      f32x4 b4 = *(const f32x4*)(bp + it * 1024 + v * 256 + lane * 4);
      i32x4 m4 = *(const i32x4*)(mp + it * 1024 + v * 256 + lane * 4);
      fs += (b4[0] + b4[1]) + (b4[2] + b4[3]);
      is += (m4[0] + m4[1]) + (m4[2] + m4[3]);
    }
  }
  sink[(size_t)lid * 256 + t] = fs + (float)is;
}

// --------------------------------------------------------------------
// Kernel 3: output projection. out[8192,1024] = Vals @ Wout[1024,1024]^T
// --------------------------------------------------------------------
__global__ __launch_bounds__(256) void k_out(const bf16* __restrict__ X,
                                             const float* __restrict__ W,
                                             float* __restrict__ Out) {
  constexpr int K = 1024;
  __shared__ __align__(16) bf16 As[128 * 64];
  __shared__ __align__(16) bf16 Bs[128 * 64];
  const int t = threadIdx.x;
  const int lane = t & 63, w = t >> 6;
  const int wr = w >> 1, wc = w & 1;
  const int li = lane & 15, g = lane >> 4;
  const int m0 = (blockIdx.x & 63) * 128;   // 64 m-tiles
  const int n0 = (blockIdx.x >> 6) * 128;   // 8 n-tiles

  f32x4 acc[4][4] = {};

  for (int kt = 0; kt < K; kt += 64) {
#pragma unroll
    for (int it = 0; it < 4; ++it) {
      int c = it * 256 + t;
      int row = c >> 3, col = (c & 7) << 3;
      gload_lds16(X + (size_t)(m0 + row) * K + kt + col, As + c * 8);
      *(bf16x8*)(Bs + c * 8) = cvt8(W + (size_t)(n0 + row) * K + kt + col);
    }
    __syncthreads();
#pragma unroll
    for (int kk = 0; kk < 2; ++kk) {
      bf16x8 af[4], bfr[4];
#pragma unroll
      for (int i = 0; i < 4; ++i)
        af[i] = *(const bf16x8*)(As + (wr * 64 + i * 16 + li) * 64 + kk * 32 + g * 8);
#pragma unroll
      for (int j = 0; j < 4; ++j)
        bfr[j] = *(const bf16x8*)(Bs + (wc * 64 + j * 16 + li) * 64 + kk * 32 + g * 8);
#pragma unroll
      for (int i = 0; i < 4; ++i)
#pragma unroll
        for (int j = 0; j < 4; ++j)
          acc[i][j] = MFMA_BF16(af[i], bfr[j], acc[i][j]);
    }
    __syncthreads();
  }

#pragma unroll
  for (int i = 0; i < 4; ++i) {
#pragma unroll
    for (int j = 0; j < 4; ++j) {
      int col = n0 + wc * 64 + j * 16 + li;
#pragma unroll
      for (int rg = 0; rg < 4; ++rg) {
        int row = m0 + wr * 64 + i * 16 + g * 4 + rg;
        Out[((size_t)row << 10) + col] = acc[i][j][rg];
      }
    }
  }
}

// --------------------------------------------------------------------
extern "C" void kernel_launch(void* const* d_in, const int* in_sizes, int n_in,
                              void* d_out, int out_size, void* d_ws, size_t ws_size,
                              hipStream_t stream) {
  const float* emb  = (const float*)d_in[0];
  const int*   mask = (const int*)d_in[1];
  const float* bias = (const float*)d_in[2];
  const float* Wqkv = (const float*)d_in[3];
  const float* Wout = (const float*)d_in[4];
  float* out = (float*)d_out;

  const size_t HEADS_ELEMS = (size_t)8 * 16 * 1024 * 64;  // 8.39M elems
  bf16* Q    = (bf16*)d_ws;
  bf16* Kc   = Q + HEADS_ELEMS;
  bf16* Vt   = Kc + HEADS_ELEMS;
  bf16* Vals = Vt + HEADS_ELEMS;
  const size_t used = 4 * HEADS_ELEMS * sizeof(bf16);  // 67,108,864 B

  k_qkv<<<dim3(64 * 24), 256, 0, stream>>>(emb, Wqkv, Q, Kc, Vt);
  k_attn<<<dim3(2048), 256, 0, stream>>>(Q, Kc, Vt, bias, mask, Vals);
  k_out<<<dim3(64 * 8), 256, 0, stream>>>(Vals, Wout, out);

  // diagnostics last (write only to scratch past the live buffers)
  if (ws_size >= used + (size_t)4 * 1024 * 1024) {
    float* sink = (float*)((char*)d_ws + used);
    k_diag_pat <<<dim3(1024), 256, 0, stream>>>(bias, mask, sink);
    k_diag_flat<<<dim3(1024), 256, 0, stream>>>(bias, mask, sink);
  }
}

// Round 10
// 543.070 us; speedup vs baseline: 1.3616x; 1.3616x over previous
//
#include <hip/hip_runtime.h>
#include <cstdint>
#include <cstddef>

// ====================================================================
// Attention block: out = softmax(mask? NEG : (QK^T*scale + bias)) V @ Wout^T
// B=8 L=1024 E=1024 H=16 A=64.
// float inputs -> const float*, bool mask -> const int*, output -> float*.
// k_attn v6: ZERO LDS in the loop. Swapped QK^T (S^T in regs) AND swapped
// PV (O^T = mfma(V^T, P^T)) with P^T assembled in-register via
// v_cvt_pk_bf16_f32 + v_permlane32/16_swap pair-merges. No DS ops ->
// no merged lgkm/vm waitcnt drain -> bias/mask/K/V loads stay in flight.
// Softmax state is per-lane (q = lane&15): no cross-lane corr shuffles.
// ====================================================================

typedef __bf16 bf16;
typedef __attribute__((ext_vector_type(8))) __bf16 bf16x8;
typedef __attribute__((ext_vector_type(4))) __bf16 bf16x4;
typedef __attribute__((ext_vector_type(4))) float f32x4;
typedef __attribute__((ext_vector_type(4))) int i32x4;

#define MFMA_BF16(a, b, c) __builtin_amdgcn_mfma_f32_16x16x32_bf16(a, b, c, 0, 0, 0)

static constexpr float SCALE_ = 0.125f;                     // 64^-0.5
static constexpr float NEGF  = -3.4028234663852886e38f;     // finfo(f32).min

__device__ __forceinline__ void gload_lds16(const bf16* g, bf16* l) {
  __builtin_amdgcn_global_load_lds((const __attribute__((address_space(1))) void*)g,
                                   (__attribute__((address_space(3))) void*)l,
                                   16, 0, 0);
}

__device__ __forceinline__ bf16x8 cvt8(const float* p) {
  f32x4 a = *(const f32x4*)p;
  f32x4 b = *(const f32x4*)(p + 4);
  bf16x8 r = {(bf16)a[0], (bf16)a[1], (bf16)a[2], (bf16)a[3],
              (bf16)b[0], (bf16)b[1], (bf16)b[2], (bf16)b[3]};
  return r;
}

// --------------------------------------------------------------------
// Kernel 1: QKV projection.  C[8192,3072] = X[8192,1024] @ W[3072,1024]^T
// --------------------------------------------------------------------
__global__ __launch_bounds__(256) void k_qkv(const float* __restrict__ X,
                                             const float* __restrict__ W,
                                             bf16* __restrict__ Q,
                                             bf16* __restrict__ Kc,
                                             bf16* __restrict__ Vt) {
  constexpr int K = 1024;
  __shared__ __align__(16) bf16 As[128 * 64];
  __shared__ __align__(16) bf16 Bs[128 * 64];
  const int t = threadIdx.x;
  const int lane = t & 63, w = t >> 6;
  const int wr = w >> 1, wc = w & 1;
  const int li = lane & 15, g = lane >> 4;
  const int m0 = (blockIdx.x & 63) * 128;   // 64 m-tiles
  const int n0 = (blockIdx.x >> 6) * 128;   // 24 n-tiles

  f32x4 acc[4][4] = {};

  for (int kt = 0; kt < K; kt += 64) {
#pragma unroll
    for (int it = 0; it < 4; ++it) {
      int c = it * 256 + t;               // 0..1023, 8 bf16 elems each
      int row = c >> 3, col = (c & 7) << 3;
      *(bf16x8*)(As + c * 8) = cvt8(X + (size_t)(m0 + row) * K + kt + col);
      *(bf16x8*)(Bs + c * 8) = cvt8(W + (size_t)(n0 + row) * K + kt + col);
    }
    __syncthreads();
#pragma unroll
    for (int kk = 0; kk < 2; ++kk) {
      bf16x8 af[4], bfr[4];
#pragma unroll
      for (int i = 0; i < 4; ++i)
        af[i] = *(const bf16x8*)(As + (wr * 64 + i * 16 + li) * 64 + kk * 32 + g * 8);
#pragma unroll
      for (int j = 0; j < 4; ++j)
        bfr[j] = *(const bf16x8*)(Bs + (wc * 64 + j * 16 + li) * 64 + kk * 32 + g * 8);
#pragma unroll
      for (int i = 0; i < 4; ++i)
#pragma unroll
        for (int j = 0; j < 4; ++j)
          acc[i][j] = MFMA_BF16(af[i], bfr[j], acc[i][j]);
    }
    __syncthreads();
  }

#pragma unroll
  for (int i = 0; i < 4; ++i) {
#pragma unroll
    for (int j = 0; j < 4; ++j) {
      int col = n0 + wc * 64 + j * 16 + li;
      int h = col / 192, r = col % 192;
#pragma unroll
      for (int rg = 0; rg < 4; ++rg) {
        int row = m0 + wr * 64 + i * 16 + g * 4 + rg;
        int b = row >> 10, l = row & 1023;
        bf16 v = (bf16)acc[i][j][rg];
        if (r < 64)
          Q[((size_t)((b * 16 + h) * 1024 + l)) * 64 + r] = v;
        else if (r < 128)
          Kc[((size_t)((b * 16 + h) * 1024 + l)) * 64 + (r - 64)] = v;
        else
          Vt[((size_t)((b * 16 + h) * 64 + (r - 128))) * 1024 + l] = v;
      }
    }
  }
}

// --------------------------------------------------------------------
// Kernel 2: flash attention, LDS-free. Grid 2048: bh = lid&127, qt=lid>>7.
// Per wave 16 q rows (q = q0 + li). S^T layout:
//   s[kkf][rg] = S[q0+li][kkt + kkf*16 + g*4 + rg]
// PV swapped: oaccT[af] = O^T block: O[q0+li][af*16 + g*4 + rg].
// P^T B-fragment built in-register: cvt_pk pairs then
// permlane32_swap + permlane16_swap pair-merges (no LDS, no shuffles
// for softmax state: m,l are per-lane).
// --------------------------------------------------------------------
__global__ __launch_bounds__(256, 4) void k_attn(const bf16* __restrict__ Q,
                                                 const bf16* __restrict__ Kc,
                                                 const bf16* __restrict__ Vt,
                                                 const float* __restrict__ bias,
                                                 const int* __restrict__ mask,
                                                 bf16* __restrict__ Vals) {
  const int t = threadIdx.x, lane = t & 63, w = t >> 6;
  const int li = lane & 15, g = lane >> 4;
  const int lid = blockIdx.x;
  const int bh = lid & 127;            // b*16+h
  const int qt = lid >> 7;
  const int b = bh >> 4, h = bh & 15;
  const int q0 = qt * 64 + w * 16;     // wave's 16 q rows

  const bf16* Qbase = Q + ((size_t)bh << 10) * 64;
  const bf16* Kbase = Kc + ((size_t)bh << 10) * 64;
  const bf16* Vbase = Vt + ((size_t)bh << 6) * 1024;
  const float* brow = bias + ((size_t)bh << 20) + (size_t)(q0 + li) * 1024 + g * 4;
  const int*   mrow = mask + ((size_t)bh << 20) + (size_t)(q0 + li) * 1024 + g * 4;

  bf16x8 qf[2];
#pragma unroll
  for (int c = 0; c < 2; ++c)
    qf[c] = *(const bf16x8*)(Qbase + (size_t)(q0 + li) * 64 + c * 32 + g * 8);

  f32x4 oaccT[4] = {};                 // O^T: O[q=li][d = af*16 + g*4 + rg]
  float mrun = NEGF;                   // per-lane (q = li)
  float lrun = 0.f;

  // ---- prologue: issue tile-0 bias/mask loads ----
  f32x4 b4[4];
  i32x4 m4[4];
#pragma unroll
  for (int kkf = 0; kkf < 4; ++kkf) {
    b4[kkf] = *(const f32x4*)(brow + kkf * 16);
    m4[kkf] = *(const i32x4*)(mrow + kkf * 16);
  }

  for (int kt6 = 0; kt6 < 16; ++kt6) {
    const int kkt = kt6 * 64;

    // ---- consume prefetched bias/mask: fold mask into bias ----
    f32x4 c4[4];
#pragma unroll
    for (int kkf = 0; kkf < 4; ++kkf)
#pragma unroll
      for (int rg = 0; rg < 4; ++rg)
        c4[kkf][rg] = m4[kkf][rg] ? NEGF : b4[kkf][rg];

    // ---- issue next tile's bias/mask loads ----
    if (kt6 < 15) {
#pragma unroll
      for (int kkf = 0; kkf < 4; ++kkf) {
        b4[kkf] = *(const f32x4*)(brow + kkt + 64 + kkf * 16);
        m4[kkf] = *(const i32x4*)(mrow + kkt + 64 + kkf * 16);
      }
    }

    // ---- S^T = K Q^T ----
    f32x4 s[4];
#pragma unroll
    for (int kkf = 0; kkf < 4; ++kkf) {
      f32x4 ss = {0.f, 0.f, 0.f, 0.f};
#pragma unroll
      for (int c = 0; c < 2; ++c) {
        bf16x8 kf = *(const bf16x8*)(Kbase + (size_t)(kkt + kkf * 16 + li) * 64 + c * 32 + g * 8);
        ss = MFMA_BF16(kf, qf[c], ss);
      }
      s[kkf] = ss;
    }

    // ---- scale + masked-bias, row max (reduce across g only) ----
    float tmax = NEGF;
#pragma unroll
    for (int kkf = 0; kkf < 4; ++kkf) {
#pragma unroll
      for (int rg = 0; rg < 4; ++rg) {
        float sv = __builtin_fmaf(s[kkf][rg], SCALE_, c4[kkf][rg]);
        s[kkf][rg] = sv;
        tmax = fmaxf(tmax, sv);
      }
    }
    tmax = fmaxf(tmax, __shfl_xor(tmax, 16));
    tmax = fmaxf(tmax, __shfl_xor(tmax, 32));

    const float mnew = fmaxf(mrun, tmax);
    const float corr = __expf(mrun - mnew);   // per-lane, row-correct
    float psum = 0.f;

    // ---- P = exp(s - m) in f32 (held in s) ----
#pragma unroll
    for (int kkf = 0; kkf < 4; ++kkf) {
#pragma unroll
      for (int rg = 0; rg < 4; ++rg) {
        float p = __expf(s[kkf][rg] - mnew);
        s[kkf][rg] = p;
        psum += p;
      }
    }
    psum += __shfl_xor(psum, 16);
    psum += __shfl_xor(psum, 32);
    lrun = lrun * corr + psum;
    mrun = mnew;

    // ---- rescale O^T (per-lane corr, no shuffles) ----
#pragma unroll
    for (int af = 0; af < 4; ++af)
#pragma unroll
      for (int rg = 0; rg < 4; ++rg) oaccT[af][rg] *= corr;

    // ---- assemble P^T B-fragments in-register ----
    // Wp[kkf][h] = bf16pack(p[kkf][2h], p[kkf][2h+1])
    uint32_t Wp[4][2];
#pragma unroll
    for (int kkf = 0; kkf < 4; ++kkf) {
#pragma unroll
      for (int hh = 0; hh < 2; ++hh) {
        uint32_t wpk;
        asm("v_cvt_pk_bf16_f32 %0, %1, %2"
            : "=v"(wpk) : "v"(s[kkf][2 * hh]), "v"(s[kkf][2 * hh + 1]));
        Wp[kkf][hh] = wpk;
      }
    }
    bf16x8 bfrag[2];
#pragma unroll
    for (int c = 0; c < 2; ++c) {
      uint32_t A0 = Wp[2 * c][0], A1 = Wp[2 * c][1];
      uint32_t B0 = Wp[2 * c + 1][0], B1 = Wp[2 * c + 1][1];
      asm("v_permlane32_swap_b32 %0, %1" : "+v"(A0), "+v"(B0));
      asm("v_permlane32_swap_b32 %0, %1" : "+v"(A1), "+v"(B1));
      asm("v_permlane16_swap_b32 %0, %1" : "+v"(A0), "+v"(B0));
      asm("v_permlane16_swap_b32 %0, %1" : "+v"(A1), "+v"(B1));
      union { uint32_t u[4]; bf16x8 v; } bu;
      bu.u[0] = A0; bu.u[1] = A1; bu.u[2] = B0; bu.u[3] = B1;
      bfrag[c] = bu.v;
    }

    // ---- O^T += V^T P^T ----
#pragma unroll
    for (int c = 0; c < 2; ++c) {
#pragma unroll
      for (int af = 0; af < 4; ++af) {
        bf16x8 vf = *(const bf16x8*)(Vbase + (size_t)(af * 16 + li) * 1024 + kkt + c * 32 + g * 8);
        oaccT[af] = MFMA_BF16(vf, bfrag[c], oaccT[af]);
      }
    }
  }

  const float linv = 1.0f / lrun;      // per-lane (q = li)
  const int q = q0 + li;
#pragma unroll
  for (int af = 0; af < 4; ++af) {
    bf16x4 o = {(bf16)(oaccT[af][0] * linv), (bf16)(oaccT[af][1] * linv),
                (bf16)(oaccT[af][2] * linv), (bf16)(oaccT[af][3] * linv)};
    *(bf16x4*)(Vals + (((size_t)(b * 1024 + q)) << 10) + h * 64 + af * 16 + g * 4) = o;
  }
}

// --------------------------------------------------------------------
// Kernel 3: output projection. out[8192,1024] = Vals @ Wout[1024,1024]^T
// --------------------------------------------------------------------
__global__ __launch_bounds__(256) void k_out(const bf16* __restrict__ X,
                                             const float* __restrict__ W,
                                             float* __restrict__ Out) {
  constexpr int K = 1024;
  __shared__ __align__(16) bf16 As[128 * 64];
  __shared__ __align__(16) bf16 Bs[128 * 64];
  const int t = threadIdx.x;
  const int lane = t & 63, w = t >> 6;
  const int wr = w >> 1, wc = w & 1;
  const int li = lane & 15, g = lane >> 4;
  const int m0 = (blockIdx.x & 63) * 128;   // 64 m-tiles
  const int n0 = (blockIdx.x >> 6) * 128;   // 8 n-tiles

  f32x4 acc[4][4] = {};

  for (int kt = 0; kt < K; kt += 64) {
#pragma unroll
    for (int it = 0; it < 4; ++it) {
      int c = it * 256 + t;
      int row = c >> 3, col = (c & 7) << 3;
      gload_lds16(X + (size_t)(m0 + row) * K + kt + col, As + c * 8);
      *(bf16x8*)(Bs + c * 8) = cvt8(W + (size_t)(n0 + row) * K + kt + col);
    }
    __syncthreads();
#pragma unroll
    for (int kk = 0; kk < 2; ++kk) {
      bf16x8 af[4], bfr[4];
#pragma unroll
      for (int i = 0; i < 4; ++i)
        af[i] = *(const bf16x8*)(As + (wr * 64 + i * 16 + li) * 64 + kk * 32 + g * 8);
#pragma unroll
      for (int j = 0; j < 4; ++j)
        bfr[j] = *(const bf16x8*)(Bs + (wc * 64 + j * 16 + li) * 64 + kk * 32 + g * 8);
#pragma unroll
      for (int i = 0; i < 4; ++i)
#pragma unroll
        for (int j = 0; j < 4; ++j)
          acc[i][j] = MFMA_BF16(af[i], bfr[j], acc[i][j]);
    }
    __syncthreads();
  }

#pragma unroll
  for (int i = 0; i < 4; ++i) {
#pragma unroll
    for (int j = 0; j < 4; ++j) {
      int col = n0 + wc * 64 + j * 16 + li;
#pragma unroll
      for (int rg = 0; rg < 4; ++rg) {
        int row = m0 + wr * 64 + i * 16 + g * 4 + rg;
        Out[((size_t)row << 10) + col] = acc[i][j][rg];
      }
    }
  }
}

// --------------------------------------------------------------------
extern "C" void kernel_launch(void* const* d_in, const int* in_sizes, int n_in,
                              void* d_out, int out_size, void* d_ws, size_t ws_size,
                              hipStream_t stream) {
  const float* emb  = (const float*)d_in[0];
  const int*   mask = (const int*)d_in[1];
  const float* bias = (const float*)d_in[2];
  const float* Wqkv = (const float*)d_in[3];
  const float* Wout = (const float*)d_in[4];
  float* out = (float*)d_out;

  const size_t HEADS_ELEMS = (size_t)8 * 16 * 1024 * 64;  // 8.39M elems
  bf16* Q    = (bf16*)d_ws;
  bf16* Kc   = Q + HEADS_ELEMS;
  bf16* Vt   = Kc + HEADS_ELEMS;
  bf16* Vals = Vt + HEADS_ELEMS;   // total ~67 MiB of ws

  k_qkv<<<dim3(64 * 24), 256, 0, stream>>>(emb, Wqkv, Q, Kc, Vt);
  k_attn<<<dim3(2048), 256, 0, stream>>>(Q, Kc, Vt, bias, mask, Vals);
  k_out<<<dim3(64 * 8), 256, 0, stream>>>(Vals, Wout, out);
}